// Round 5
// baseline (28.076 us; speedup 1.0000x reference)
//
#include <hip/hip_runtime.h>
#include <math.h>

#define NOUT 64
#define NIN  64
#define HH   32
#define WW   32

#define NREC      (NOUT * 9 * NIN)      // 36864 records
#define WPK_ELEMS (NREC * 12)           // 442368 floats
#define WN_WORDS  (NOUT * NIN * 9 * 6)  // 221184
#define WD_WORDS  (NOUT * NIN * 9 * 4)  // 147456

// ---------- prep: pack weights to wpk[f][ab][c][12]; coalesced linear reads ----------
__global__ __launch_bounds__(256) void wpack_kernel(const float* __restrict__ wn,
                                                    const float* __restrict__ wd,
                                                    float* __restrict__ wpk) {
    int idx = blockIdx.x * 256 + threadIdx.x;      // grid covers WN_WORDS+WD_WORDS exactly
    if (idx < WN_WORDS) {
        // src linear: ((f*64 + c)*9 + ab)*6 + n
        int n  = idx % 6;
        int t  = idx / 6;
        int ab = t % 9;
        int t2 = t / 9;
        int c  = t2 & 63;
        int f  = t2 >> 6;
        wpk[((f * 9 + ab) * 64 + c) * 12 + n] = wn[idx];
    } else {
        int id2 = idx - WN_WORDS;
        // src linear: ((f*64 + c)*9 + ab)*4 + n
        int n  = id2 & 3;
        int t  = id2 >> 2;
        int ab = t % 9;
        int t2 = t / 9;
        int c  = t2 & 63;
        int f  = t2 >> 6;
        wpk[((f * 9 + ab) * 64 + c) * 12 + 6 + n] = wd[id2];
    }
}

// ---------- main: block = (f, 2-row band); x tile in LDS; lane = c ----------
__global__ __launch_bounds__(512, 8) void kan_main(const float* __restrict__ x,
                                                   const float* __restrict__ wpk,
                                                   float* __restrict__ out) {
    __shared__ float xt[4 * 34 * 64];              // 34816 B: rows i0-1..i0+2, cols -1..32

    // bijective XCD-chunked swizzle: 1024 blocks, 128 per XCD
    int bid  = blockIdx.x;
    int wgid = (bid & 7) * 128 + (bid >> 3);
    int f    = wgid >> 4;                          // 8 f's per XCD
    int band = wgid & 15;
    int i0   = band * 2;

    int tid  = threadIdx.x;
    int lane = tid & 63;                           // = input channel c
    int wave = tid >> 6;

    // ---- stage padded x tile: 8704 floats = 17 * 512, coalesced (lane=c contiguous) ----
#pragma unroll
    for (int k = 0; k < 17; ++k) {
        int idx = k * 512 + tid;
        int c   = idx & 63;
        int pos = idx >> 6;                        // 0..135
        int col = pos % 34;                        // 0..33 -> gj = col-1
        int t   = pos / 34;                        // 0..3  -> gi = i0-1+t
        int gi  = i0 - 1 + t;
        int gj  = col - 1;
        float v = 0.0f;
        if (gi >= 0 && gi < HH && gj >= 0 && gj < WW)
            v = x[(gi * WW + gj) * NIN + c];
        xt[idx] = v;
    }
    __syncthreads();

    int wr = wave >> 2;                            // row within band: 0..1
    int j0 = (wave & 3) * 8;                       // pixel quarter
    int i  = i0 + wr;

    float acc[8];
#pragma unroll
    for (int p = 0; p < 8; ++p) acc[p] = 0.0f;

    const float4* w4 = (const float4*)(wpk + ((size_t)(f * 9) * 64 + lane) * 12);

#pragma unroll 2
    for (int ab = 0; ab < 9; ++ab) {
        const int a = ab / 3, b = ab % 3;
        float4 wA = w4[ab * 192 + 0];              // a0 a1 a2 a3
        float4 wB = w4[ab * 192 + 1];              // a4 a5 b0 b1
        float4 wC = w4[ab * 192 + 2];              // b2 b3  -  -

        const float* xb = &xt[((wr + a) * 34 + (j0 + b)) * 64 + lane];
#pragma unroll
        for (int p = 0; p < 8; ++p) {
            float xv = xb[p * 64];                 // ds_read_b32, imm offset, 2-way alias (free)
            float pn = fmaf(wB.y, xv, wB.x);       // a5*x + a4
            pn = fmaf(pn, xv, wA.w);
            pn = fmaf(pn, xv, wA.z);
            pn = fmaf(pn, xv, wA.y);
            pn = fmaf(pn, xv, wA.x);
            float qn = fmaf(wC.y, xv, wC.x);       // b3*x + b2
            qn = fmaf(qn, xv, wB.w);
            qn = fmaf(qn, xv, wB.z);
            float den = 1.0f + fabsf(xv * qn);
            acc[p] = fmaf(pn, __builtin_amdgcn_rcpf(den), acc[p]);
        }
    }

    // ---- reduce over lanes (channels); write once ----
#pragma unroll
    for (int p = 0; p < 8; ++p) {
        float s = acc[p];
        s += __shfl_xor(s, 32, 64);
        s += __shfl_xor(s, 16, 64);
        s += __shfl_xor(s, 8, 64);
        s += __shfl_xor(s, 4, 64);
        s += __shfl_xor(s, 2, 64);
        s += __shfl_xor(s, 1, 64);
        if (lane == p) out[f * (HH * WW) + i * WW + j0 + p] = s;
    }
}

// ---------- fallback (tiny ws): direct NHWC gather, write-once ----------
__global__ __launch_bounds__(256) void kan_fallback(const float* __restrict__ x,
                                                    const float* __restrict__ wn,
                                                    const float* __restrict__ wd,
                                                    float* __restrict__ out) {
    __shared__ float red[256];
    int bid = blockIdx.x;
    int t = bid & 15;
    int f = bid >> 4;
    int tid = threadIdx.x;
    int g = tid >> 6;
    int p = tid & 63;
    int r = p >> 5;
    int j = p & 31;
    int i = t * 2 + r;
    int c0 = g * 16;
    const float* wnb = wn + (f * NIN + c0) * 9 * 6;
    const float* wdb = wd + (f * NIN + c0) * 9 * 4;
    float acc = 0.0f;
    for (int c = 0; c < 16; ++c) {
        float xv[9];
#pragma unroll
        for (int a = 0; a < 3; ++a)
#pragma unroll
            for (int b = 0; b < 3; ++b) {
                int ii = i + a - 1, jj = j + b - 1;
                bool inb = (ii >= 0) && (ii < HH) && (jj >= 0) && (jj < WW);
                xv[a * 3 + b] = inb ? x[(ii * WW + jj) * NIN + (c0 + c)] : 0.0f;
            }
        const float* wnc = wnb + c * 54;
        const float* wdc = wdb + c * 36;
#pragma unroll
        for (int ab = 0; ab < 9; ++ab) {
            float xx = xv[ab];
            float pn = fmaf(wnc[ab * 6 + 5], xx, wnc[ab * 6 + 4]);
            pn = fmaf(pn, xx, wnc[ab * 6 + 3]);
            pn = fmaf(pn, xx, wnc[ab * 6 + 2]);
            pn = fmaf(pn, xx, wnc[ab * 6 + 1]);
            pn = fmaf(pn, xx, wnc[ab * 6 + 0]);
            float qn = fmaf(wdc[ab * 4 + 3], xx, wdc[ab * 4 + 2]);
            qn = fmaf(qn, xx, wdc[ab * 4 + 1]);
            qn = fmaf(qn, xx, wdc[ab * 4 + 0]);
            float den = 1.0f + fabsf(xx * qn);
            acc = fmaf(pn, __builtin_amdgcn_rcpf(den), acc);
        }
    }
    red[tid] = acc;
    __syncthreads();
    if (tid < 64) {
        float s = red[tid] + red[tid + 64] + red[tid + 128] + red[tid + 192];
        int rr = tid >> 5;
        int jj = tid & 31;
        out[f * (HH * WW) + (t * 2 + rr) * WW + jj] = s;
    }
}

extern "C" void kernel_launch(void* const* d_in, const int* in_sizes, int n_in,
                              void* d_out, int out_size, void* d_ws, size_t ws_size,
                              hipStream_t stream) {
    const float* x  = (const float*)d_in[0];
    const float* wn = (const float*)d_in[1];
    const float* wd = (const float*)d_in[2];
    float* out = (float*)d_out;

    const size_t need = (size_t)WPK_ELEMS * sizeof(float);

    if (ws_size >= need) {
        float* wpk = (float*)d_ws;
        const int pack_total = WN_WORDS + WD_WORDS;   // 368640 = 1440 * 256
        wpack_kernel<<<pack_total / 256, 256, 0, stream>>>(wn, wd, wpk);
        kan_main<<<1024, 512, 0, stream>>>(x, wpk, out);
    } else {
        kan_fallback<<<NOUT * 16, 256, 0, stream>>>(x, wn, wd, out);
    }
}

// Round 6
// 23.591 us; speedup vs baseline: 1.1901x; 1.1901x over previous
//
#include <hip/hip_runtime.h>
#include <math.h>

#define NOUT 64
#define NIN  64
#define HH   32
#define WW   32
#define XSTR 137                        // LDS row stride (odd -> conflict-free scatter)

// ---------- single kernel: block = (f, 2-row band); wave = 8-channel group;
// ---------- lanes = 64 pixels (2 rows x 32 cols); weights via scalar pipe ----------
__global__ __launch_bounds__(512, 8) void kan_main(const float* __restrict__ x,
                                                   const float* __restrict__ wn,
                                                   const float* __restrict__ wd,
                                                   float* __restrict__ out) {
    __shared__ float xt[NIN * XSTR];    // 35072 B: xt[c][pos], pos = t*34+col (4 rows x 34 cols)
    __shared__ float red[512];          // cross-wave c-reduction

    // bijective XCD-chunked swizzle: 1024 blocks, 128 per XCD -> 8 f's per XCD L2
    int bid  = blockIdx.x;
    int wgid = (bid & 7) * 128 + (bid >> 3);
    int f    = wgid >> 4;
    int band = wgid & 15;
    int i0   = band * 2;

    int tid = threadIdx.x;

    // ---- stage x tile: 8704 floats = 17 * 512; global reads lane=c coalesced;
    // ---- ds_write addr = c*137 + pos -> bank (9c)%32 -> 2-way alias (free) ----
#pragma unroll
    for (int k = 0; k < 17; ++k) {
        int idx = k * 512 + tid;
        int c   = idx & 63;
        int pos = idx >> 6;             // 0..135
        int t   = pos / 34;
        int col = pos % 34;
        int gi  = i0 - 1 + t;
        int gj  = col - 1;
        float v = 0.0f;
        if (gi >= 0 && gi < HH && gj >= 0 && gj < WW)
            v = x[(gi * WW + gj) * NIN + c];
        xt[c * XSTR + pos] = v;
    }
    __syncthreads();

    int lane = tid & 63;
    int wv   = __builtin_amdgcn_readfirstlane(tid >> 6);  // c-group 0..7 (SGPR)
    int r    = lane >> 5;               // row within band
    int j    = lane & 31;               // col

    float acc = 0.0f;

    const float* wnf = wn + (size_t)(f * NIN + wv * 8) * 54;  // [c][ab][6]
    const float* wdf = wd + (size_t)(f * NIN + wv * 8) * 36;  // [c][ab][4]

    for (int cc = 0; cc < 8; ++cc) {
        const float* wnc = wnf + cc * 54;   // uniform -> s_load
        const float* wdc = wdf + cc * 36;
        const float* xc  = &xt[(wv * 8 + cc) * XSTR + r * 34 + j];
#pragma unroll
        for (int a = 0; a < 3; ++a) {
#pragma unroll
            for (int b = 0; b < 3; ++b) {
                const int ab = a * 3 + b;
                float xv = xc[a * 34 + b];          // ds_read_b32, imm offset, 2-way alias
                float pn = fmaf(wnc[ab * 6 + 5], xv, wnc[ab * 6 + 4]);
                pn = fmaf(pn, xv, wnc[ab * 6 + 3]);
                pn = fmaf(pn, xv, wnc[ab * 6 + 2]);
                pn = fmaf(pn, xv, wnc[ab * 6 + 1]);
                pn = fmaf(pn, xv, wnc[ab * 6 + 0]);
                float qn = fmaf(wdc[ab * 4 + 3], xv, wdc[ab * 4 + 2]);
                qn = fmaf(qn, xv, wdc[ab * 4 + 1]);
                qn = fmaf(qn, xv, wdc[ab * 4 + 0]);
                float den = 1.0f + fabsf(xv * qn);
                acc = fmaf(pn, __builtin_amdgcn_rcpf(den), acc);
            }
        }
    }

    // ---- reduce the 8 c-group partials per pixel; write once, coalesced ----
    red[tid] = acc;
    __syncthreads();
    if (tid < 64) {
        float s = red[tid]       + red[tid + 64]  + red[tid + 128] + red[tid + 192]
                + red[tid + 256] + red[tid + 320] + red[tid + 384] + red[tid + 448];
        int rr = tid >> 5;
        int jj = tid & 31;
        out[f * (HH * WW) + (i0 + rr) * WW + jj] = s;
    }
}

extern "C" void kernel_launch(void* const* d_in, const int* in_sizes, int n_in,
                              void* d_out, int out_size, void* d_ws, size_t ws_size,
                              hipStream_t stream) {
    const float* x  = (const float*)d_in[0];
    const float* wn = (const float*)d_in[1];
    const float* wd = (const float*)d_in[2];
    float* out = (float*)d_out;
    (void)d_ws; (void)ws_size;

    kan_main<<<1024, 512, 0, stream>>>(x, wn, wd, out);
}